// Round 10
// baseline (228.536 us; speedup 1.0000x reference)
//
#include <hip/hip_runtime.h>
#include <math.h>

#define DIM      64
#define N_MEM    32
#define N_ENTITY 500000
#define N_REL    32
#define N_ITEM   10000
#define HOPS     2
#define BATCH    4096
#define HIST     50

typedef float4 f4;
typedef float v4f __attribute__((ext_vector_type(4)));

// ---------------------------------------------------------------------------
// Tiny pass: rdot[r] = dot(relation[r], w_r) for 32 relations.
// ---------------------------------------------------------------------------
__global__ __launch_bounds__(256) void ripple_rdot(
    const float* __restrict__ relation_emb,
    const float* __restrict__ W_w,
    float* __restrict__ rdot)           // [N_REL]
{
    const int wave = (blockIdx.x * blockDim.x + threadIdx.x) >> 6;
    const int lane = threadIdx.x & 63;
    const int g = lane >> 4;
    const int p = lane & 15;
    const int r = wave * 4 + g;
    if (r >= N_REL) return;
    const f4 wr = ((const f4*)W_w)[16 + p];
    const f4 r4 = ((const f4*)relation_emb)[(size_t)r * 16 + p];
    float vr = r4.x * wr.x + r4.y * wr.y + r4.z * wr.z + r4.w * wr.w;
    vr += __shfl_xor(vr, 1, 64);
    vr += __shfl_xor(vr, 2, 64);
    vr += __shfl_xor(vr, 4, 64);
    vr += __shfl_xor(vr, 8, 64);
    if (p == 0) rdot[r] = vr;
}

// ---------------------------------------------------------------------------
// Stage 1: one wave per (item, hop); lane = g*16+p. The 16 head/tail row
// gathers are issued as explicit sc0 (agent-scope, L1-bypass) dwordx4 loads
// so ALL 16 stay in flight (R5's VGPR=52 shows the compiler was splitting
// them ~8+8). Drain via s_waitcnt tied to the results.
// ---------------------------------------------------------------------------
__global__ __launch_bounds__(256) void ripple_stage1(
    const float* __restrict__ W_w,
    const float* __restrict__ W_b,
    const int*   __restrict__ heads,
    const int*   __restrict__ relations,
    const int*   __restrict__ tails,
    const float* __restrict__ entity_emb,
    const float* __restrict__ rdot,
    float*       __restrict__ accp)      // [N_ITEM][HOPS][DIM]
{
    const int wave = (blockIdx.x * blockDim.x + threadIdx.x) >> 6;  // = h*N_ITEM + i
    const int lane = threadIdx.x & 63;
    if (wave >= HOPS * N_ITEM) return;
    const int h = wave < N_ITEM ? 0 : 1;
    const int i = wave - h * N_ITEM;
    const int g = lane >> 4;
    const int p = lane & 15;

    const f4* __restrict__ E4 = (const f4*)entity_emb;
    const f4* __restrict__ W4 = (const f4*)W_w;

    const f4 wh = W4[p];
    const f4 wt = W4[32 + p];
    const float bias = W_b[0];

    const int base = wave * N_MEM + g;   // this lane's m = 4k+g

    // ---- Phase 0: indices ----
    int hi[8], ri[8], ti[8];
#pragma unroll
    for (int k = 0; k < 8; ++k) {
        hi[k] = heads[base + 4 * k];
        ri[k] = relations[base + 4 * k];
        ti[k] = tails[base + 4 * k];
    }

    // ---- Phase A: 16 sc0 row-gathers, all forced in flight ----
    v4f he[8], te[8];
#pragma unroll
    for (int k = 0; k < 8; ++k) {
        const f4* ap = E4 + (size_t)hi[k] * 16 + p;
        asm volatile("global_load_dwordx4 %0, %1, off sc0"
                     : "=v"(he[k]) : "v"(ap));
    }
#pragma unroll
    for (int k = 0; k < 8; ++k) {
        const f4* ap = E4 + (size_t)ti[k] * 16 + p;
        asm volatile("global_load_dwordx4 %0, %1, off sc0"
                     : "=v"(te[k]) : "v"(ap));
    }

    // relation logits (L1-resident 128B table) — overlaps the gathers
    float lr[8];
#pragma unroll
    for (int k = 0; k < 8; ++k) lr[k] = rdot[ri[k]];

    // ---- drain: tie every result to a waitcnt so nothing is consumed early ----
#pragma unroll
    for (int k = 0; k < 8; ++k)
        asm volatile("s_waitcnt vmcnt(0)" : "+v"(he[k]), "+v"(te[k]));

    float part[8];
#pragma unroll
    for (int k = 0; k < 8; ++k) {
        part[k] = he[k].x * wh.x + he[k].y * wh.y + he[k].z * wh.z + he[k].w * wh.w
                + te[k].x * wt.x + te[k].y * wt.y + te[k].z * wt.z + te[k].w * wt.w;
    }

    // ---- Phase B: 16-lane reduces (4 memories in parallel), sigmoid+exp ----
    float e[8];
    float se = 0.f;
#pragma unroll
    for (int k = 0; k < 8; ++k) {
        float v = part[k];
        v += __shfl_xor(v, 1, 64);
        v += __shfl_xor(v, 2, 64);
        v += __shfl_xor(v, 4, 64);
        v += __shfl_xor(v, 8, 64);
        const float logit = v + lr[k] + bias;
        const float sig   = 1.f / (1.f + __expf(-logit));
        const float ex    = __expf(sig);
        e[k] = ex;
        se += ex;
    }
    se += __shfl_xor(se, 16, 64);
    se += __shfl_xor(se, 32, 64);
    const float inv = 1.f / se;

    // ---- Phase C: weighted tail sum from registers ----
    f4 acc = {0.f, 0.f, 0.f, 0.f};
#pragma unroll
    for (int k = 0; k < 8; ++k) {
        const float w = e[k] * inv;
        acc.x += w * te[k].x;
        acc.y += w * te[k].y;
        acc.z += w * te[k].z;
        acc.w += w * te[k].w;
    }

    acc.x += __shfl_xor(acc.x, 16, 64);
    acc.x += __shfl_xor(acc.x, 32, 64);
    acc.y += __shfl_xor(acc.y, 16, 64);
    acc.y += __shfl_xor(acc.y, 32, 64);
    acc.z += __shfl_xor(acc.z, 16, 64);
    acc.z += __shfl_xor(acc.z, 32, 64);
    acc.w += __shfl_xor(acc.w, 16, 64);
    acc.w += __shfl_xor(acc.w, 32, 64);
    if (g == 0) ((f4*)accp)[((size_t)i * 2 + h) * 16 + p] = acc;
}

// folded[i] = entity[item_ids[i]] + accp[i][0] + accp[i][1]
__global__ __launch_bounds__(256) void ripple_fold(
    const float* __restrict__ entity_emb,
    const int*   __restrict__ item_ids,
    const float* __restrict__ accp,
    float*       __restrict__ folded)
{
    const int t = blockIdx.x * blockDim.x + threadIdx.x;
    if (t >= N_ITEM * 16) return;
    const int i = t >> 4;
    const int p = t & 15;
    const f4* __restrict__ E4 = (const f4*)entity_emb;
    const f4* __restrict__ A4 = (const f4*)accp;
    const f4 a  = A4[(size_t)i * 32 + p];
    const f4 b  = A4[(size_t)i * 32 + 16 + p];
    const f4 it = E4[(size_t)item_ids[i] * 16 + p];
    f4 r;
    r.x = it.x + a.x + b.x;
    r.y = it.y + a.y + b.y;
    r.z = it.z + a.z + b.z;
    r.w = it.w + a.w + b.w;
    ((f4*)folded)[(size_t)i * 16 + p] = r;
}

__global__ __launch_bounds__(256) void ripple_stage2(
    const float* __restrict__ entity_emb,
    const int*   __restrict__ records_idx,
    const int*   __restrict__ items,
    const float* __restrict__ folded,
    float*       __restrict__ out)
{
    const int wave = (blockIdx.x * blockDim.x + threadIdx.x) >> 6;
    const int lane = threadIdx.x & 63;
    if (wave >= BATCH) return;
    const int b = wave;
    const int g = lane >> 4;
    const int p = lane & 15;

    const f4* __restrict__ A4 = (const f4*)folded;
    const f4* __restrict__ E4 = (const f4*)entity_emb;

    const int rb = b * HIST;
    int idx[13];
    float wgt[13];
#pragma unroll
    for (int k = 0; k < 13; ++k) {
        const int j  = 4 * k + g;
        const int jc = j < HIST ? j : (HIST - 1);
        wgt[k] = j < HIST ? 1.f : 0.f;
        idx[k] = records_idx[rb + jc];
    }

    f4 user = {0.f, 0.f, 0.f, 0.f};
#pragma unroll
    for (int k = 0; k < 13; ++k) {
        const f4 r = A4[(size_t)idx[k] * 16 + p];
        user.x += wgt[k] * r.x;
        user.y += wgt[k] * r.y;
        user.z += wgt[k] * r.z;
        user.w += wgt[k] * r.w;
    }
    user.x += __shfl_xor(user.x, 16, 64);
    user.x += __shfl_xor(user.x, 32, 64);
    user.y += __shfl_xor(user.y, 16, 64);
    user.y += __shfl_xor(user.y, 32, 64);
    user.z += __shfl_xor(user.z, 16, 64);
    user.z += __shfl_xor(user.z, 32, 64);
    user.w += __shfl_xor(user.w, 16, 64);
    user.w += __shfl_xor(user.w, 32, 64);

    const f4 pair = E4[(size_t)items[b] * 16 + p];
    float dot = user.x * pair.x + user.y * pair.y + user.z * pair.z + user.w * pair.w;
    dot += __shfl_xor(dot, 1, 64);
    dot += __shfl_xor(dot, 2, 64);
    dot += __shfl_xor(dot, 4, 64);
    dot += __shfl_xor(dot, 8, 64);
    if (lane == 0) out[b] = 1.f / (1.f + __expf(-dot));
}

extern "C" void kernel_launch(void* const* d_in, const int* in_sizes, int n_in,
                              void* d_out, int out_size, void* d_ws, size_t ws_size,
                              hipStream_t stream) {
    const float* entity_emb   = (const float*)d_in[0];
    const float* relation_emb = (const float*)d_in[1];
    const float* W_w          = (const float*)d_in[2];
    const float* W_b          = (const float*)d_in[3];
    const int*   item_ids     = (const int*)d_in[4];
    const int*   heads        = (const int*)d_in[5];
    const int*   relations    = (const int*)d_in[6];
    const int*   tails        = (const int*)d_in[7];
    const int*   records_idx  = (const int*)d_in[8];
    const int*   items        = (const int*)d_in[9];
    float* out = (float*)d_out;

    float* rdot   = (float*)d_ws;                          // 128 B
    float* accp   = rdot + N_REL;                          // 5.12 MB
    float* folded = accp + (size_t)N_ITEM * HOPS * DIM;    // 2.56 MB

    ripple_rdot<<<2, 256, 0, stream>>>(relation_emb, W_w, rdot);

    const int waves1  = HOPS * N_ITEM;          // 20000 waves, 4 per block
    const int blocks1 = (waves1 + 3) / 4;
    ripple_stage1<<<blocks1, 256, 0, stream>>>(W_w, W_b, heads, relations, tails,
                                               entity_emb, rdot, accp);

    const int blocksF = (N_ITEM * 16 + 255) / 256;
    ripple_fold<<<blocksF, 256, 0, stream>>>(entity_emb, item_ids, accp, folded);

    const int blocks2 = (BATCH + 3) / 4;
    ripple_stage2<<<blocks2, 256, 0, stream>>>(entity_emb, records_idx, items,
                                               folded, out);
}